// Round 6
// baseline (496.783 us; speedup 1.0000x reference)
//
#include <hip/hip_runtime.h>

typedef _Float16 half_t;
typedef __attribute__((ext_vector_type(8))) _Float16 f16x8;
typedef __attribute__((ext_vector_type(4))) _Float16 f16x4;
typedef __attribute__((ext_vector_type(4))) float    f32x4;

// ---------------------------------------------------------------------------
// gemm1: q = fp16(emb[skills]) @ W  -> qh fp16 [8192][1024]
//        also writes sk (f32, exact) into out[:, 0:512]  (nt==0 blocks only)
// W transposed f32->fp16 in-kernel. tile 64x256, 4 waves (2x2), K-chunks 64,
// swizzled LDS, BT-pattern MFMA.
// ---------------------------------------------------------------------------
__global__ __launch_bounds__(256, 2) void gemm1_kernel(
    const void* __restrict__ skills_raw, const float* __restrict__ emb,
    const float* __restrict__ W, half_t* __restrict__ qh,
    float* __restrict__ out)
{
    __shared__ __align__(16) half_t As[64 * 64];
    __shared__ __align__(16) half_t Bs[256 * 64];
    int wg = blockIdx.x;
    int mt = wg >> 2, nt = wg & 3;
    int m0 = mt * 64, n0 = nt * 256;
    int t = threadIdx.x, wid = t >> 6, lane = t & 63;
    int l15 = lane & 15, l4 = lane >> 4;
    int wm = wid >> 1, wn = wid & 1;

    // skills dtype auto-detect (int64 staging => odd int32 words all zero)
    const int* s32 = (const int*)skills_raw;
    const long long* s64 = (const long long*)skills_raw;
    bool is64 = true;
#pragma unroll
    for (int ii = 0; ii < 32; ++ii) is64 = is64 && (s32[2 * ii + 1] == 0);

    f32x4 acc[2][8];
#pragma unroll
    for (int mi = 0; mi < 2; ++mi)
#pragma unroll
        for (int ni = 0; ni < 8; ++ni) acc[mi][ni] = (f32x4){0.f, 0.f, 0.f, 0.f};

    for (int kk = 0; kk < 512; kk += 64) {
        // stage A: gathered embedding rows, f32 -> fp16 (+ f32 sk output, exact)
#pragma unroll
        for (int i = 0; i < 4; ++i) {
            int task = t + 256 * i;
            int r = task >> 4, c = (task & 15) * 4;
            int idx = m0 + r;
            int sid = is64 ? (int)s64[idx] : s32[idx];
            sid = sid < 0 ? 0 : (sid > 20000 ? 20000 : sid);   // OOB guard
            float4 v = *(const float4*)(emb + (long)sid * 512 + kk + c);
            f16x4 h4 = {(half_t)v.x, (half_t)v.y, (half_t)v.z, (half_t)v.w};
            *(f16x4*)(As + r * 64 + (c ^ ((r & 7) << 3))) = h4;
            if (nt == 0) {
                *(float4*)(out + ((long)idx) * 1536 + kk + c) = v;
            }
        }
        // stage B: transpose W[kk..kk+64][n0..n0+256] f32 -> Bs[n][k] fp16
#pragma unroll
        for (int i = 0; i < 4; ++i) {
            int task = t + 256 * i;            // 0..1023
            int k0g = (task & 15) * 4;         // k offset 0..60
            int nn0 = (task >> 4) * 4;         // n offset 0..252
            const float* sp = W + (long)(kk + k0g) * 1024 + n0 + nn0;
            float4 r0 = *(const float4*)(sp);
            float4 r1 = *(const float4*)(sp + 1024);
            float4 r2 = *(const float4*)(sp + 2048);
            float4 r3 = *(const float4*)(sp + 3072);
            { int nn = nn0 + 0; f16x4 w = {(half_t)r0.x,(half_t)r1.x,(half_t)r2.x,(half_t)r3.x};
              *(f16x4*)(Bs + nn * 64 + (k0g ^ ((nn & 7) << 3))) = w; }
            { int nn = nn0 + 1; f16x4 w = {(half_t)r0.y,(half_t)r1.y,(half_t)r2.y,(half_t)r3.y};
              *(f16x4*)(Bs + nn * 64 + (k0g ^ ((nn & 7) << 3))) = w; }
            { int nn = nn0 + 2; f16x4 w = {(half_t)r0.z,(half_t)r1.z,(half_t)r2.z,(half_t)r3.z};
              *(f16x4*)(Bs + nn * 64 + (k0g ^ ((nn & 7) << 3))) = w; }
            { int nn = nn0 + 3; f16x4 w = {(half_t)r0.w,(half_t)r1.w,(half_t)r2.w,(half_t)r3.w};
              *(f16x4*)(Bs + nn * 64 + (k0g ^ ((nn & 7) << 3))) = w; }
        }
        __syncthreads();
#pragma unroll
        for (int ks = 0; ks < 2; ++ks) {
            int kb = ks * 32 + (l4 << 3);
            f16x8 a[2];
#pragma unroll
            for (int mi = 0; mi < 2; ++mi) {
                int ar = wm * 32 + mi * 16 + l15;
                a[mi] = *(const f16x8*)(As + ar * 64 + (kb ^ ((ar & 7) << 3)));
            }
#pragma unroll
            for (int ni = 0; ni < 8; ++ni) {
                int br = wn * 128 + ni * 16 + l15;
                f16x8 bb = *(const f16x8*)(Bs + br * 64 + (kb ^ ((br & 7) << 3)));
                acc[0][ni] = __builtin_amdgcn_mfma_f32_16x16x32_f16(a[0], bb, acc[0][ni], 0, 0, 0);
                acc[1][ni] = __builtin_amdgcn_mfma_f32_16x16x32_f16(a[1], bb, acc[1][ni], 0, 0, 0);
            }
        }
        __syncthreads();
    }
    // epilogue: q fp16
#pragma unroll
    for (int mi = 0; mi < 2; ++mi)
#pragma unroll
        for (int ni = 0; ni < 8; ++ni)
#pragma unroll
            for (int r = 0; r < 4; ++r) {
                int row = m0 + wm * 32 + mi * 16 + l4 * 4 + r;
                int col = n0 + wn * 128 + ni * 16 + l15;
                qh[(long)row * 1024 + col] = (half_t)acc[mi][ni][r];
            }
}

// ---------------------------------------------------------------------------
// attn: per (batch, 32-row q tile): scores=q@desc^T (f32 acc in regs),
//       wave-parallel softmax, P(fp16,LDS), ctx=P@desc (V^T built in-kernel
//       from f32 desc), f32 out. Static LDS 103,424 B.
// ---------------------------------------------------------------------------
__global__ __launch_bounds__(256, 1) void attn_kernel(
    const half_t* __restrict__ qh, const float* __restrict__ desc,
    float* __restrict__ out)
{
    __shared__ __align__(16) char smem[103424];
    half_t* qs  = (half_t*)(smem);            // [32][64]   phase A
    half_t* dsb = (half_t*)(smem + 4096);     // [512][64]  phase A
    half_t* Pl  = (half_t*)(smem + 69632);    // [32][512]  softmax->phase C
    half_t* vt  = (half_t*)(smem);            // [1024][32] phase C (aliases qs/dsb)
    float* smax = (float*)(smem + 102400);    // [4][32]
    float* ssum = (float*)(smem + 102912);    // [4][32]

    // XCD-aware remap: 4 q-tiles of a batch land on one XCD (shared desc in L2)
    int i = blockIdx.x;
    int b  = (i & 7) + 8 * (i >> 5);
    int qt = (i >> 3) & 3;
    int s0 = qt * 32;
    int t = threadIdx.x, wid = t >> 6, lane = t & 63;
    int l15 = lane & 15, l4 = lane >> 4;

    const half_t* qbase  = qh + ((long)(b * 128 + s0)) * 1024;
    const float*  dbasef = desc + ((long)b * 512) * 1024;

    // ---- phase A: scores [32][512], wave w holds cols [128w,128w+128) ----
    f32x4 accs[2][8];
#pragma unroll
    for (int mi = 0; mi < 2; ++mi)
#pragma unroll
        for (int ni = 0; ni < 8; ++ni) accs[mi][ni] = (f32x4){0.f, 0.f, 0.f, 0.f};

    for (int kk = 0; kk < 1024; kk += 64) {
        {   // stage q (32x64) from fp16 qh
            int r = t >> 3, c = (t & 7) * 8;
            f16x8 v = *(const f16x8*)(qbase + (long)r * 1024 + kk + c);
            *(f16x8*)(qs + r * 64 + (c ^ ((r & 7) << 3))) = v;
        }
#pragma unroll
        for (int i2 = 0; i2 < 16; ++i2) {   // stage desc rows (512x64) f32->fp16
            int task = t + 256 * i2;
            int r = task >> 3, c = (task & 7) * 8;
            const float* sp = dbasef + (long)r * 1024 + kk + c;
            float4 v0 = *(const float4*)(sp);
            float4 v1 = *(const float4*)(sp + 4);
            f16x8 h8 = {(half_t)v0.x,(half_t)v0.y,(half_t)v0.z,(half_t)v0.w,
                        (half_t)v1.x,(half_t)v1.y,(half_t)v1.z,(half_t)v1.w};
            *(f16x8*)(dsb + r * 64 + (c ^ ((r & 7) << 3))) = h8;
        }
        __syncthreads();
#pragma unroll
        for (int ks = 0; ks < 2; ++ks) {
            int kb = ks * 32 + (l4 << 3);
            f16x8 a[2];
#pragma unroll
            for (int mi = 0; mi < 2; ++mi) {
                int ar = mi * 16 + l15;
                a[mi] = *(const f16x8*)(qs + ar * 64 + (kb ^ ((ar & 7) << 3)));
            }
#pragma unroll
            for (int ni = 0; ni < 8; ++ni) {
                int br = wid * 128 + ni * 16 + l15;
                f16x8 bb = *(const f16x8*)(dsb + br * 64 + (kb ^ ((br & 7) << 3)));
                accs[0][ni] = __builtin_amdgcn_mfma_f32_16x16x32_f16(a[0], bb, accs[0][ni], 0, 0, 0);
                accs[1][ni] = __builtin_amdgcn_mfma_f32_16x16x32_f16(a[1], bb, accs[1][ni], 0, 0, 0);
            }
        }
        __syncthreads();
    }

    // ---- softmax (lane holds rows mi*16 + l4*4 + r at col l15-slices) ----
    float pm[2][4];
#pragma unroll
    for (int mi = 0; mi < 2; ++mi)
#pragma unroll
        for (int r = 0; r < 4; ++r) {
            float m = -1e30f;
#pragma unroll
            for (int ni = 0; ni < 8; ++ni) m = fmaxf(m, accs[mi][ni][r]);
            pm[mi][r] = m;
        }
#pragma unroll
    for (int off = 1; off < 16; off <<= 1)
#pragma unroll
        for (int mi = 0; mi < 2; ++mi)
#pragma unroll
            for (int r = 0; r < 4; ++r)
                pm[mi][r] = fmaxf(pm[mi][r], __shfl_xor(pm[mi][r], off, 64));
    if (l15 == 0) {
#pragma unroll
        for (int mi = 0; mi < 2; ++mi)
#pragma unroll
            for (int r = 0; r < 4; ++r)
                smax[wid * 32 + mi * 16 + l4 * 4 + r] = pm[mi][r];
    }
    __syncthreads();
    float mt[2][4], psum[2][4];
#pragma unroll
    for (int mi = 0; mi < 2; ++mi)
#pragma unroll
        for (int r = 0; r < 4; ++r) {
            int row = mi * 16 + l4 * 4 + r;
            mt[mi][r] = fmaxf(fmaxf(smax[row], smax[32 + row]),
                              fmaxf(smax[64 + row], smax[96 + row]));
            psum[mi][r] = 0.f;
        }
#pragma unroll
    for (int mi = 0; mi < 2; ++mi)
#pragma unroll
        for (int ni = 0; ni < 8; ++ni)
#pragma unroll
            for (int r = 0; r < 4; ++r) {
                float p = __expf(accs[mi][ni][r] - mt[mi][r]);
                psum[mi][r] += p;
                int row = mi * 16 + l4 * 4 + r;
                int col = wid * 128 + ni * 16 + l15;
                Pl[row * 512 + (col ^ ((row & 7) << 3))] = (half_t)p;
            }
#pragma unroll
    for (int off = 1; off < 16; off <<= 1)
#pragma unroll
        for (int mi = 0; mi < 2; ++mi)
#pragma unroll
            for (int r = 0; r < 4; ++r)
                psum[mi][r] += __shfl_xor(psum[mi][r], off, 64);
    if (l15 == 0) {
#pragma unroll
        for (int mi = 0; mi < 2; ++mi)
#pragma unroll
            for (int r = 0; r < 4; ++r)
                ssum[wid * 32 + mi * 16 + l4 * 4 + r] = psum[mi][r];
    }
    __syncthreads();

    // ---- phase C: ctx = P @ V, V^T tile built from f32 desc in-kernel ----
    f32x4 accc[2][16];
#pragma unroll
    for (int mi = 0; mi < 2; ++mi)
#pragma unroll
        for (int ni = 0; ni < 16; ++ni) accc[mi][ni] = (f32x4){0.f, 0.f, 0.f, 0.f};

    for (int l0 = 0; l0 < 512; l0 += 32) {
        // stage vt[h][l'] = desc[l0+l'][h], fp16, pos = l' ^ ((h&3)<<3)
#pragma unroll
        for (int i2 = 0; i2 < 8; ++i2) {
            int task = t + 256 * i2;           // 0..2047
            int lg4 = (task & 7) * 4;          // local l 0..28
            int h0  = (task >> 3) * 4;         // 0..1020
            const float* sp = dbasef + (long)(l0 + lg4) * 1024 + h0;
            float4 r0 = *(const float4*)(sp);
            float4 r1 = *(const float4*)(sp + 1024);
            float4 r2 = *(const float4*)(sp + 2048);
            float4 r3 = *(const float4*)(sp + 3072);
            { int h = h0 + 0; f16x4 w = {(half_t)r0.x,(half_t)r1.x,(half_t)r2.x,(half_t)r3.x};
              *(f16x4*)(vt + h * 32 + (lg4 ^ ((h & 3) << 3))) = w; }
            { int h = h0 + 1; f16x4 w = {(half_t)r0.y,(half_t)r1.y,(half_t)r2.y,(half_t)r3.y};
              *(f16x4*)(vt + h * 32 + (lg4 ^ ((h & 3) << 3))) = w; }
            { int h = h0 + 2; f16x4 w = {(half_t)r0.z,(half_t)r1.z,(half_t)r2.z,(half_t)r3.z};
              *(f16x4*)(vt + h * 32 + (lg4 ^ ((h & 3) << 3))) = w; }
            { int h = h0 + 3; f16x4 w = {(half_t)r0.w,(half_t)r1.w,(half_t)r2.w,(half_t)r3.w};
              *(f16x4*)(vt + h * 32 + (lg4 ^ ((h & 3) << 3))) = w; }
        }
        __syncthreads();
        int kb = l4 << 3;
        f16x8 a[2];
#pragma unroll
        for (int mi = 0; mi < 2; ++mi) {
            int ar = mi * 16 + l15;
            a[mi] = *(const f16x8*)(Pl + ar * 512 + ((l0 + kb) ^ ((ar & 7) << 3)));
        }
#pragma unroll
        for (int ni = 0; ni < 16; ++ni) {
            int br = wid * 256 + ni * 16 + l15;
            f16x8 bb = *(const f16x8*)(vt + br * 32 + (kb ^ ((br & 3) << 3)));
            accc[0][ni] = __builtin_amdgcn_mfma_f32_16x16x32_f16(a[0], bb, accc[0][ni], 0, 0, 0);
            accc[1][ni] = __builtin_amdgcn_mfma_f32_16x16x32_f16(a[1], bb, accc[1][ni], 0, 0, 0);
        }
        __syncthreads();
    }

    // ---- epilogue: normalize + f32 out[:, 512:1536] ----
    float rinv[2][4];
#pragma unroll
    for (int mi = 0; mi < 2; ++mi)
#pragma unroll
        for (int r = 0; r < 4; ++r) {
            int row = mi * 16 + l4 * 4 + r;
            rinv[mi][r] = 1.f / (ssum[row] + ssum[32 + row] + ssum[64 + row] + ssum[96 + row]);
        }
#pragma unroll
    for (int mi = 0; mi < 2; ++mi)
#pragma unroll
        for (int ni = 0; ni < 16; ++ni)
#pragma unroll
            for (int r = 0; r < 4; ++r) {
                int row = mi * 16 + l4 * 4 + r;
                int col = wid * 256 + ni * 16 + l15;
                long oidx = ((long)(b * 128 + s0 + row)) * 1536 + 512 + col;
                out[oidx] = accc[mi][ni][r] * rinv[mi][r];
            }
}

// ---------------------------------------------------------------------------
extern "C" void kernel_launch(void* const* d_in, const int* in_sizes, int n_in,
                              void* d_out, int out_size, void* d_ws, size_t ws_size,
                              hipStream_t stream)
{
    // map inputs by unique element counts (defensive vs ordering)
    const void* skills = nullptr;
    const float *desc = nullptr, *emb = nullptr, *W = nullptr;
    for (int i = 0; i < n_in; ++i) {
        switch (in_sizes[i]) {
            case 8192:     skills = d_in[i]; break;              // 64*128
            case 33554432: desc = (const float*)d_in[i]; break;  // 64*512*1024
            case 10240512: emb  = (const float*)d_in[i]; break;  // 20001*512
            case 524288:   W    = (const float*)d_in[i]; break;  // 512*1024
        }
    }
    if (!skills) skills = d_in[0];
    if (!desc)   desc   = (const float*)d_in[1];
    if (!emb)    emb    = (const float*)d_in[2];
    if (!W)      W      = (const float*)d_in[3];

    half_t* qh = (half_t*)d_ws;                       // 16 MiB — only ws use
    float* out = (float*)d_out;                       // f32 (reference dtype)

    hipLaunchKernelGGL(gemm1_kernel, dim3(512), dim3(256), 0, stream,
                       skills, emb, W, qh, out);
    hipLaunchKernelGGL(attn_kernel, dim3(256), dim3(256), 0, stream,
                       qh, desc, out);
}